// Round 4
// baseline (189.710 us; speedup 1.0000x reference)
//
#include <hip/hip_runtime.h>
#include <math.h>

#define NU 32768
#define NI 16384
#define DH 64
#define KK 50

typedef unsigned short ushort_t;
typedef __attribute__((ext_vector_type(8))) short  bf16x8;
typedef __attribute__((ext_vector_type(4))) float  f32x4;
typedef __attribute__((ext_vector_type(4))) unsigned int u32x4;

__device__ __forceinline__ unsigned cvtpk(float lo, float hi) {
    unsigned r;
    asm("v_cvt_pk_bf16_f32 %0, %1, %2" : "=v"(r) : "v"(lo), "v"(hi));
    return r;
}
__device__ __forceinline__ bf16x8 as_bf(u32x4 v) {
    union { u32x4 u; bf16x8 b; } x; x.u = v; return x.b;
}

// ---------------------------------------------------------------------------
// prep: gate pack (float4 layout, f32) + teA: A-fragment-tiled bf16 te
//   teA[((t*2+s)*64 + l)*8 + j] = bf16(te[16t + (l&15)][32s + 8*(l>>4) + j])
//   (rows >= KK zeroed)
// ---------------------------------------------------------------------------
__global__ __launch_bounds__(256) void prep_kernel(
    const float* __restrict__ gate_u, const float* __restrict__ gate_i,
    const float* __restrict__ u_te,   const float* __restrict__ i_te,
    float* __restrict__ gT_u, float* __restrict__ gT_i,
    ushort_t* __restrict__ teA_u, ushort_t* __restrict__ teA_i)
{
    int t0 = blockIdx.x * 256 + threadIdx.x;
    int stride = gridDim.x * 256;
    for (int i = t0; i < DH * 2 * DH; i += stride) {
        int d = i >> 7, j = i & 127;
        int dst = (j >> 2) * 256 + d * 4 + (j & 3);
        gT_u[dst] = gate_u[i];
        gT_i[dst] = gate_i[i];
    }
    for (int i = t0; i < 4096; i += stride) {
        int j = i & 7, l = (i >> 3) & 63, s = (i >> 9) & 1, t = (i >> 10) & 3;
        int r = t * 16 + (l & 15);
        int d = s * 32 + (l >> 4) * 8 + j;
        float vu = (r < KK) ? u_te[r * DH + d] : 0.f;
        float vi = (r < KK) ? i_te[r * DH + d] : 0.f;
        unsigned ub = __float_as_uint(vu); ub += 0x7fffu + ((ub >> 16) & 1u);
        unsigned ib = __float_as_uint(vi); ib += 0x7fffu + ((ib >> 16) & 1u);
        teA_u[i] = (ushort_t)(ub >> 16);
        teA_i[i] = (ushort_t)(ib >> 16);
    }
}

// ---------------------------------------------------------------------------
// proj: h = feat @ W.T (fp32) + bf16 copy for gathers  (unchanged, verified)
// ---------------------------------------------------------------------------
__global__ __launch_bounds__(256) void proj_kernel(
    const float* __restrict__ feat, const float* __restrict__ W,
    float* __restrict__ h, ushort_t* __restrict__ hbf, int N)
{
    __shared__ float Wl[64 * 65];
    const int lane = threadIdx.x & 63;
    const int w = threadIdx.x >> 6;
    for (int i = threadIdx.x; i < 4096; i += 256)
        Wl[(i >> 6) * 65 + (i & 63)] = W[i];
    __syncthreads();
    int row0 = blockIdx.x * 32 + w * 8;
    for (int r = 0; r < 8; ++r) {
        int n = row0 + r;
        float fv = feat[n * DH + lane];
        float acc = 0.f;
        #pragma unroll
        for (int k = 0; k < DH; ++k)
            acc = fmaf(__shfl(fv, k), Wl[lane * 65 + k], acc);
        h[n * DH + lane] = acc;
        unsigned int ub = __float_as_uint(acc);
        ub += 0x7fffu + ((ub >> 16) & 1u);          // RNE to bf16
        hbf[n * DH + lane] = (ushort_t)(ub >> 16);
    }
}

// ---------------------------------------------------------------------------
// agg: 128 threads = 2 waves = 2 independent nodes. No __syncthreads.
// Gather iteration (t,s) loads 16B that IS the MFMA A-fragment for mail
// tile t, K-chunk s (lane l -> row 16t+l%16, d = 32s+8*(l>>4)+j). The same
// registers are stored to a row-major XOR-swizzled LDS mail for the scalar
// weighted loop. Dot (e,e1) and tp run as MFMA; softmax/weighted/gate keep
// the verified R2 scalar code.
// Per-wave LDS: mail[64][128B] swizzled (8192) + EB f32[320] (1280).
// ---------------------------------------------------------------------------
__global__ __launch_bounds__(128, 3) void agg_kernel(
    const ushort_t* __restrict__ h_src_bf,  // bf16 source embeddings
    const float*    __restrict__ h_dst,     // fp32 dst embeddings
    const float*    __restrict__ feat_dst,  // residual
    const int*      __restrict__ nbr,
    const int*      __restrict__ times,
    const ushort_t* __restrict__ teA,       // tiled A-frags of te (bf16)
    const float*    __restrict__ te_k,      // raw [50][64] f32
    const float*    __restrict__ gT4,       // packed gate f32
    float*          __restrict__ out)
{
    __shared__ __align__(16) char SM[2][9472];

    const int wid  = threadIdx.x >> 6;
    const int lane = threadIdx.x & 63;
    const int n    = blockIdx.x * 2 + wid;
    char*  mailb = SM[wid];
    float* EB    = (float*)(SM[wid] + 8192);   // e[64] e1[64] tp[64] cc[128]

    const int c = lane & 15;
    const int g = lane >> 4;

    // ---- per-wave loads ----
    int my_t = 0, my_nb = 0;
    if (lane < KK) {
        my_t  = times[n * KK + lane];
        my_nb = nbr[n * KK + lane];
    }

    // ---- gather: af[t][s] register A-frags + swizzled row-major LDS copy ----
    u32x4 af[4][2];
    #pragma unroll
    for (int t = 0; t < 4; ++t) {
        int r = t * 16 + c;
        int idx = __builtin_amdgcn_ds_bpermute(r << 2, my_nb);   // junk rows>=50 read row of nb 0 (safe)
        const ushort_t* src = h_src_bf + idx * DH;
        #pragma unroll
        for (int s = 0; s < 2; ++s) {
            u32x4 v = *(const u32x4*)(src + s * 32 + g * 8);
            af[t][s] = v;
            unsigned bo = (unsigned)(r * 128)
                        + (((unsigned)(s * 64 + g * 16)) ^ (((unsigned)(c & 7)) << 4));
            *(u32x4*)(mailb + bo) = v;
        }
    }

    // ---- stable ranks: sro[k] = #{j<KK: key_j > key_k} ----
    int key = my_t * 64 + lane;
    int sro = 0;
    #pragma unroll
    for (int j = 0; j < KK; ++j) {
        int kj = __builtin_amdgcn_readlane(key, j);
        sro += (kj > key) ? 1 : 0;
    }

    // ---- last = first argmax(times) (wave-uniform) ----
    int key2 = (lane < KK) ? (my_t * 64 + (63 - lane)) : -1;
    #pragma unroll
    for (int off = 32; off >= 1; off >>= 1) {
        int o = __shfl_xor(key2, off);
        key2 = key2 > o ? key2 : o;
    }
    const int last   = __builtin_amdgcn_readfirstlane(63 - (key2 & 63));
    const int t_last = last >> 4;
    const int c_last = last & 15;

    // ---- B-fragments: col0 = bf16(dst), col1 = sle = mail[last] ----
    unsigned fb[2][4];
    {
        // dst part from f32 global
        unsigned dp[2][4];
        #pragma unroll
        for (int s = 0; s < 2; ++s) {
            const float* hd = h_dst + n * DH + s * 32 + g * 8;
            float4 u0 = *(const float4*)(hd);
            float4 u1 = *(const float4*)(hd + 4);
            dp[s][0] = cvtpk(u0.x, u0.y);
            dp[s][1] = cvtpk(u0.z, u0.w);
            dp[s][2] = cvtpk(u1.x, u1.y);
            dp[s][3] = cvtpk(u1.z, u1.w);
        }
        // sle part: pull af[t_last][s] u32s from lane (l&48)+c_last
        u32x4 sl0, sl1;
        if      (t_last == 0) { sl0 = af[0][0]; sl1 = af[0][1]; }
        else if (t_last == 1) { sl0 = af[1][0]; sl1 = af[1][1]; }
        else if (t_last == 2) { sl0 = af[2][0]; sl1 = af[2][1]; }
        else                  { sl0 = af[3][0]; sl1 = af[3][1]; }
        const int ba = ((lane & 48) + c_last) << 2;
        unsigned sb[2][4];
        #pragma unroll
        for (int u = 0; u < 4; ++u) {
            sb[0][u] = (unsigned)__builtin_amdgcn_ds_bpermute(ba, (int)sl0[u]);
            sb[1][u] = (unsigned)__builtin_amdgcn_ds_bpermute(ba, (int)sl1[u]);
        }
        const bool is1 = (c == 1);
        #pragma unroll
        for (int s = 0; s < 2; ++s)
            #pragma unroll
            for (int u = 0; u < 4; ++u)
                fb[s][u] = is1 ? sb[s][u] : dp[s][u];
    }
    u32x4 fbv[2];
    #pragma unroll
    for (int s = 0; s < 2; ++s) {
        fbv[s][0] = fb[s][0]; fbv[s][1] = fb[s][1];
        fbv[s][2] = fb[s][2]; fbv[s][3] = fb[s][3];
    }

    // ---- dot MFMA: e[k] (col0), e1[k] (col1) ----
    #pragma unroll
    for (int t = 0; t < 4; ++t) {
        f32x4 acc = {0.f, 0.f, 0.f, 0.f};
        #pragma unroll
        for (int s = 0; s < 2; ++s)
            acc = __builtin_amdgcn_mfma_f32_16x16x32_bf16(as_bf(af[t][s]), as_bf(fbv[s]), acc, 0, 0, 0);
        if (c < 2) {
            float* eb = EB + c * 64 + t * 16 + g * 4;
            eb[0] = acc[0]; eb[1] = acc[1]; eb[2] = acc[2]; eb[3] = acc[3];
        }
    }

    // ---- tp MFMA: tp[r] = dot(te[r], dst) via teA tiles, same B ----
    #pragma unroll
    for (int t = 0; t < 4; ++t) {
        f32x4 acc = {0.f, 0.f, 0.f, 0.f};
        #pragma unroll
        for (int s = 0; s < 2; ++s) {
            u32x4 ta = *(const u32x4*)(teA + ((t * 2 + s) * 64 + lane) * 8);
            acc = __builtin_amdgcn_mfma_f32_16x16x32_bf16(as_bf(ta), as_bf(fbv[s]), acc, 0, 0, 0);
        }
        if (c == 0) {
            float* eb = EB + 128 + t * 16 + g * 4;
            eb[0] = acc[0]; eb[1] = acc[1]; eb[2] = acc[2]; eb[3] = acc[3];
        }
    }

    // ---- softmax at lane = k ----
    float eraw  = EB[lane];
    float e1raw = EB[64 + lane];
    float tpown = EB[128 + lane];
    float tps = __uint_as_float(__builtin_amdgcn_ds_bpermute(sro << 2, __float_as_uint(tpown)));
    float e  = (lane < KK) ? (eraw + tps) * 0.125f : -INFINITY;
    float e1 = (lane < KK) ? e1raw * 0.125f        : -INFINITY;
    float m = e, m1 = e1;
    #pragma unroll
    for (int off = 32; off >= 1; off >>= 1) {
        m  = fmaxf(m,  __shfl_xor(m,  off));
        m1 = fmaxf(m1, __shfl_xor(m1, off));
    }
    float p  = (lane < KK) ? __expf(e - m)   : 0.f;
    float p1 = (lane < KK) ? __expf(e1 - m1) : 0.f;
    float s = p, s1 = p1;
    #pragma unroll
    for (int off = 32; off >= 1; off >>= 1) {
        s  += __shfl_xor(s,  off);
        s1 += __shfl_xor(s1, off);
    }
    float al  = p  * __builtin_amdgcn_rcpf(s);
    float al1 = p1 * __builtin_amdgcn_rcpf(s1);

    // ---- weighted sums, lane = d (verified scalar path) ----
    int voff[8];
    #pragma unroll
    for (int c8 = 0; c8 < 8; ++c8)
        voff[c8] = (lane * 2) ^ (c8 << 4);

    float hl = 0.f, hs = 0.f;
    #pragma unroll
    for (int k = 0; k < KK; ++k) {
        float a  = __uint_as_float(__builtin_amdgcn_readlane(__float_as_uint(al),  k));
        float a1 = __uint_as_float(__builtin_amdgcn_readlane(__float_as_uint(al1), k));
        int   sr = __builtin_amdgcn_readlane(sro, k);
        float t  = te_k[sr * DH + lane];
        ushort_t u = *(const ushort_t*)(mailb + k * 128 + voff[k & 7]);
        float mv = __uint_as_float(((unsigned int)u) << 16);
        hl = fmaf(a,  mv + t, hl);
        hs = fmaf(a1, mv,     hs);
    }

    // ---- gated output + residual + ELU (cc in EB scratch) ----
    float* cc = EB + 192;
    cc[lane]      = hl;
    cc[DH + lane] = hs;
    float gacc = 0.f;
    const float4* g4 = (const float4*)gT4;
    #pragma unroll
    for (int jb = 0; jb < 32; ++jb) {
        float4 gv = g4[jb * 64 + lane];
        float4 c4 = *(const float4*)&cc[jb * 4];
        gacc = fmaf(gv.x, c4.x, gacc);
        gacc = fmaf(gv.y, c4.y, gacc);
        gacc = fmaf(gv.z, c4.z, gacc);
        gacc = fmaf(gv.w, c4.w, gacc);
    }
    float xo = gacc + feat_dst[n * DH + lane];
    out[n * DH + lane] = xo > 0.f ? xo : (__expf(xo) - 1.0f);
}

extern "C" void kernel_launch(void* const* d_in, const int* in_sizes, int n_in,
                              void* d_out, int out_size, void* d_ws, size_t ws_size,
                              hipStream_t stream) {
    const float* user_feat = (const float*)d_in[0];
    const float* item_feat = (const float*)d_in[1];
    const float* W_user    = (const float*)d_in[2];
    const float* W_item    = (const float*)d_in[3];
    const float* gate_u    = (const float*)d_in[4];
    const float* gate_i    = (const float*)d_in[5];
    const float* u_te      = (const float*)d_in[6];
    const float* u_te_k    = (const float*)d_in[7];
    const float* i_te      = (const float*)d_in[8];
    const float* i_te_k    = (const float*)d_in[9];
    const int*   user_nbr  = (const int*)d_in[10];
    const int*   item_nbr  = (const int*)d_in[11];
    const int*   user_time = (const int*)d_in[12];
    const int*   item_time = (const int*)d_in[13];

    float* ws      = (float*)d_ws;
    float* user_h  = ws;                          // NU*64 f32
    float* item_h  = user_h + NU * DH;            // NI*64 f32
    float* gT_u    = item_h + NI * DH;            // 8192 f32
    float* gT_i    = gT_u + DH * 2 * DH;          // 8192 f32
    ushort_t* teA_u = (ushort_t*)(gT_i + DH * 2 * DH);   // 4096 ushort
    ushort_t* teA_i = teA_u + 4096;                       // 4096 ushort
    ushort_t* hbf_u = teA_i + 4096;                       // NU*64 ushort
    ushort_t* hbf_i = hbf_u + NU * DH;                    // NI*64 ushort

    float* user_out = (float*)d_out;
    float* item_out = user_out + NU * DH;

    hipLaunchKernelGGL(prep_kernel, dim3(32), dim3(256), 0, stream,
                       gate_u, gate_i, u_te, i_te, gT_u, gT_i, teA_u, teA_i);
    hipLaunchKernelGGL(proj_kernel, dim3(NU / 32), dim3(256), 0, stream,
                       user_feat, W_user, user_h, hbf_u, NU);
    hipLaunchKernelGGL(proj_kernel, dim3(NI / 32), dim3(256), 0, stream,
                       item_feat, W_item, item_h, hbf_i, NI);
    hipLaunchKernelGGL(agg_kernel, dim3(NI / 2), dim3(128), 0, stream,
                       hbf_u, item_h, item_feat, item_nbr, item_time,
                       teA_i, i_te_k, gT_i, item_out);
    hipLaunchKernelGGL(agg_kernel, dim3(NU / 2), dim3(128), 0, stream,
                       hbf_i, user_h, user_feat, user_nbr, user_time,
                       teA_u, u_te_k, gT_u, user_out);
}

// Round 5
// 188.493 us; speedup vs baseline: 1.0065x; 1.0065x over previous
//
#include <hip/hip_runtime.h>
#include <math.h>

#define NU 32768
#define NI 16384
#define DH 64
#define KK 50

typedef unsigned short ushort_t;
typedef __attribute__((ext_vector_type(8))) short  bf16x8;
typedef __attribute__((ext_vector_type(4))) float  f32x4;
typedef __attribute__((ext_vector_type(4))) unsigned int u32x4;

__device__ __forceinline__ unsigned cvtpk(float lo, float hi) {
    unsigned r;
    asm("v_cvt_pk_bf16_f32 %0, %1, %2" : "=v"(r) : "v"(lo), "v"(hi));
    return r;
}
__device__ __forceinline__ bf16x8 as_bf(u32x4 v) {
    union { u32x4 u; bf16x8 b; } x; x.u = v; return x.b;
}
__device__ __forceinline__ ushort_t bf16r(float v) {
    unsigned u = __float_as_uint(v);
    u += 0x7fffu + ((u >> 16) & 1u);
    return (ushort_t)(u >> 16);
}

// ---------------------------------------------------------------------------
// prep (grid=2, one block per relation):
//   M[d][r] = sum_d2 gate[d][d2] * te_k[r][d2]            (f32, LDS)
//   teA: A-frag tiles of te  (verified R4 layout)
//   gA:  A-frag tiles of BIG[d][k]: k<128 -> gate[d][k]; k<178 -> M[d][k-128]
// ---------------------------------------------------------------------------
__global__ __launch_bounds__(256) void prep_kernel(
    const float* __restrict__ gate_u, const float* __restrict__ gate_i,
    const float* __restrict__ u_te,   const float* __restrict__ i_te,
    const float* __restrict__ u_te_k, const float* __restrict__ i_te_k,
    ushort_t* __restrict__ teA_u, ushort_t* __restrict__ teA_i,
    ushort_t* __restrict__ gA_u,  ushort_t* __restrict__ gA_i)
{
    __shared__ float M[64 * 50];
    const int rel = blockIdx.x;
    const float* gate = rel ? gate_i : gate_u;
    const float* te   = rel ? i_te   : u_te;
    const float* tek  = rel ? i_te_k : u_te_k;
    ushort_t* teA = rel ? teA_i : teA_u;
    ushort_t* gA  = rel ? gA_i  : gA_u;

    for (int o = threadIdx.x; o < 64 * 50; o += 256) {
        int d = o / 50, r = o % 50;
        float acc = 0.f;
        #pragma unroll 8
        for (int d2 = 0; d2 < 64; ++d2)
            acc = fmaf(gate[d * 128 + d2], tek[r * 64 + d2], acc);
        M[o] = acc;
    }
    __syncthreads();
    // teA (R4-verified layout): teA[((t*2+s)*64+l)*8+j] = te[16t+(l&15)][32s+8*(l>>4)+j]
    for (int i = threadIdx.x; i < 4096; i += 256) {
        int j = i & 7, l = (i >> 3) & 63, s = (i >> 9) & 1, t = i >> 10;
        int r = t * 16 + (l & 15);
        int d = s * 32 + ((l >> 4) & 3) * 8 + j;
        teA[i] = bf16r(r < KK ? te[r * DH + d] : 0.f);
    }
    // gA: gA[((mt*6+s)*64+l)*8+j] = BIG[d=16mt+(l&15)][k=32s+8*(l>>4)+j]
    for (int i = threadIdx.x; i < 12288; i += 256) {
        int j = i & 7, l = (i >> 3) & 63, q = i >> 9;
        int s = q % 6, mt = q / 6;
        int d = mt * 16 + (l & 15);
        int k = s * 32 + ((l >> 4) & 3) * 8 + j;
        float v = 0.f;
        if (k < 128)            v = gate[d * 128 + k];
        else if (k < 128 + KK)  v = M[d * 50 + (k - 128)];
        gA[i] = bf16r(v);
    }
}

// ---------------------------------------------------------------------------
// proj: hbf = bf16(feat @ W.T)   (f32 copy no longer needed)
// ---------------------------------------------------------------------------
__global__ __launch_bounds__(256) void proj_kernel(
    const float* __restrict__ feat, const float* __restrict__ W,
    ushort_t* __restrict__ hbf, int N)
{
    __shared__ float Wl[64 * 65];
    const int lane = threadIdx.x & 63;
    const int w = threadIdx.x >> 6;
    for (int i = threadIdx.x; i < 4096; i += 256)
        Wl[(i >> 6) * 65 + (i & 63)] = W[i];
    __syncthreads();
    int row0 = blockIdx.x * 32 + w * 8;
    for (int r = 0; r < 8; ++r) {
        int n = row0 + r;
        float fv = feat[n * DH + lane];
        float acc = 0.f;
        #pragma unroll
        for (int k = 0; k < DH; ++k)
            acc = fmaf(__shfl(fv, k), Wl[lane * 65 + k], acc);
        hbf[n * DH + lane] = bf16r(acc);
    }
}

// ---------------------------------------------------------------------------
// agg: 128 threads = 2 waves = 2 nodes, no __syncthreads.
// Emits cc[n][192] bf16 = [hl_mail | hs | beta]; gate applied in epi_kernel.
// Per-wave LDS: mail rows<50 swizzled (6400B) + e/e1/tp f32 (768B) = 7168B.
// ---------------------------------------------------------------------------
__global__ __launch_bounds__(128, 5) void agg_kernel(
    const ushort_t* __restrict__ h_src_bf,
    const ushort_t* __restrict__ h_dst_bf,
    const int*      __restrict__ nbr,
    const int*      __restrict__ times,
    const ushort_t* __restrict__ teA,
    ushort_t*       __restrict__ ccout)
{
    __shared__ __align__(16) char SM[2][7168];

    const int wid  = threadIdx.x >> 6;
    const int lane = threadIdx.x & 63;
    const int n    = blockIdx.x * 2 + wid;
    char*  mailb = SM[wid];
    float* EB    = (float*)(SM[wid] + 6400);   // e[64] e1[64] tp[64]

    const int c = lane & 15;
    const int g = lane >> 4;

    int my_t = 0, my_nb = 0;
    if (lane < KK) {
        my_t  = times[n * KK + lane];
        my_nb = nbr[n * KK + lane];
    }

    // ---- gather: af register A-frags + swizzled LDS copy (rows < 50 only) ----
    u32x4 af[4][2];
    #pragma unroll
    for (int t = 0; t < 4; ++t) {
        int r = t * 16 + c;
        int idx = __builtin_amdgcn_ds_bpermute(r << 2, my_nb);
        const ushort_t* src = h_src_bf + idx * DH;
        #pragma unroll
        for (int s = 0; s < 2; ++s) {
            u32x4 v = *(const u32x4*)(src + s * 32 + g * 8);
            af[t][s] = v;
            if (t < 3 || c < 2) {
                unsigned bo = (unsigned)(r * 128)
                            + (((unsigned)(s * 64 + g * 16)) ^ (((unsigned)(c & 7)) << 4));
                *(u32x4*)(mailb + bo) = v;
            }
        }
    }

    // ---- stable ranks ----
    int key = my_t * 64 + lane;
    int sro = 0;
    #pragma unroll
    for (int j = 0; j < KK; ++j) {
        int kj = __builtin_amdgcn_readlane(key, j);
        sro += (kj > key) ? 1 : 0;
    }

    // ---- last = first argmax(times) ----
    int key2 = (lane < KK) ? (my_t * 64 + (63 - lane)) : -1;
    #pragma unroll
    for (int off = 32; off >= 1; off >>= 1) {
        int o = __shfl_xor(key2, off);
        key2 = key2 > o ? key2 : o;
    }
    const int last   = __builtin_amdgcn_readfirstlane(63 - (key2 & 63));
    const int t_last = last >> 4;
    const int c_last = last & 15;

    // ---- B-fragments: col0 = dst(bf16), col1 = sle = mail[last] ----
    u32x4 fbv[2];
    {
        const ushort_t* hd = h_dst_bf + n * DH;
        u32x4 sl0, sl1;
        if      (t_last == 0) { sl0 = af[0][0]; sl1 = af[0][1]; }
        else if (t_last == 1) { sl0 = af[1][0]; sl1 = af[1][1]; }
        else if (t_last == 2) { sl0 = af[2][0]; sl1 = af[2][1]; }
        else                  { sl0 = af[3][0]; sl1 = af[3][1]; }
        const int ba = ((lane & 48) + c_last) << 2;
        const bool is1 = (c == 1);
        #pragma unroll
        for (int s = 0; s < 2; ++s) {
            u32x4 dp = *(const u32x4*)(hd + s * 32 + g * 8);
            u32x4 sl = (s == 0) ? sl0 : sl1;
            u32x4 fb;
            #pragma unroll
            for (int u = 0; u < 4; ++u) {
                unsigned sv = (unsigned)__builtin_amdgcn_ds_bpermute(ba, (int)sl[u]);
                fb[u] = is1 ? sv : dp[u];
            }
            fbv[s] = fb;
        }
    }

    // ---- dot MFMA: e (col0), e1 (col1)  [verified R4] ----
    #pragma unroll
    for (int t = 0; t < 4; ++t) {
        f32x4 acc = {0.f, 0.f, 0.f, 0.f};
        #pragma unroll
        for (int s = 0; s < 2; ++s)
            acc = __builtin_amdgcn_mfma_f32_16x16x32_bf16(as_bf(af[t][s]), as_bf(fbv[s]), acc, 0, 0, 0);
        if (c < 2) {
            float* eb = EB + c * 64 + t * 16 + g * 4;
            eb[0] = acc[0]; eb[1] = acc[1]; eb[2] = acc[2]; eb[3] = acc[3];
        }
    }

    // ---- tp MFMA (teA)  [verified R4] ----
    #pragma unroll
    for (int t = 0; t < 4; ++t) {
        f32x4 acc = {0.f, 0.f, 0.f, 0.f};
        #pragma unroll
        for (int s = 0; s < 2; ++s) {
            u32x4 ta = *(const u32x4*)(teA + ((t * 2 + s) * 64 + lane) * 8);
            acc = __builtin_amdgcn_mfma_f32_16x16x32_bf16(as_bf(ta), as_bf(fbv[s]), acc, 0, 0, 0);
        }
        if (c == 0) {
            float* eb = EB + 128 + t * 16 + g * 4;
            eb[0] = acc[0]; eb[1] = acc[1]; eb[2] = acc[2]; eb[3] = acc[3];
        }
    }

    // ---- softmax at lane = k ----
    float eraw  = EB[lane];
    float e1raw = EB[64 + lane];
    float tpown = EB[128 + lane];
    float tps = __uint_as_float(__builtin_amdgcn_ds_bpermute(sro << 2, __float_as_uint(tpown)));
    float e  = (lane < KK) ? (eraw + tps) * 0.125f : -INFINITY;
    float e1 = (lane < KK) ? e1raw * 0.125f        : -INFINITY;
    float m = e, m1 = e1;
    #pragma unroll
    for (int off = 32; off >= 1; off >>= 1) {
        m  = fmaxf(m,  __shfl_xor(m,  off));
        m1 = fmaxf(m1, __shfl_xor(m1, off));
    }
    float p  = (lane < KK) ? __expf(e - m)   : 0.f;
    float p1 = (lane < KK) ? __expf(e1 - m1) : 0.f;
    float s = p, s1 = p1;
    #pragma unroll
    for (int off = 32; off >= 1; off >>= 1) {
        s  += __shfl_xor(s,  off);
        s1 += __shfl_xor(s1, off);
    }
    float al  = p  * __builtin_amdgcn_rcpf(s);
    float al1 = p1 * __builtin_amdgcn_rcpf(s1);

    // ---- beta scatter + cc row stores ----
    ushort_t* ccr = ccout + (size_t)n * 192;
    {
        int pushaddr = ((lane < KK) ? sro : lane) << 2;
        float beta = __uint_as_float(__builtin_amdgcn_ds_permute(pushaddr, __float_as_uint(al)));
        ccr[128 + lane] = bf16r(beta);
    }

    // ---- weighted sums (lane = d), packed-alpha readlane ----
    unsigned apk = cvtpk(al, al1);
    int voff[8];
    #pragma unroll
    for (int c8 = 0; c8 < 8; ++c8)
        voff[c8] = (lane * 2) ^ (c8 << 4);
    float hl = 0.f, hs = 0.f;
    #pragma unroll
    for (int k = 0; k < KK; ++k) {
        unsigned a = (unsigned)__builtin_amdgcn_readlane((int)apk, k);
        float av  = __uint_as_float(a << 16);
        float a1v = __uint_as_float(a & 0xffff0000u);
        ushort_t u = *(const ushort_t*)(mailb + k * 128 + voff[k & 7]);
        float mv = __uint_as_float(((unsigned)u) << 16);
        hl = fmaf(av,  mv, hl);
        hs = fmaf(a1v, mv, hs);
    }
    unsigned hp = cvtpk(hl, hs);
    ccr[lane]      = (ushort_t)hp;
    ccr[64 + lane] = (ushort_t)(hp >> 16);
}

// ---------------------------------------------------------------------------
// epi: batched gate GEMM. 1 wave = 16 nodes; A = gA tiles (d-rows),
// B = 16 cc columns; out = ELU(D + feat).
// ---------------------------------------------------------------------------
__global__ __launch_bounds__(256) void epi_kernel(
    const ushort_t* __restrict__ cc,
    const ushort_t* __restrict__ gA,
    const float*    __restrict__ feat,
    float*          __restrict__ out)
{
    const int w    = threadIdx.x >> 6;
    const int lane = threadIdx.x & 63;
    const int c = lane & 15, g = lane >> 4;
    const int nb = (blockIdx.x * 4 + w) * 16;

    const char* ccr = (const char*)(cc + (size_t)(nb + c) * 192);
    u32x4 bb[6];
    #pragma unroll
    for (int s = 0; s < 6; ++s)
        bb[s] = *(const u32x4*)(ccr + s * 64 + g * 16);

    f32x4 acc[4] = {{0,0,0,0},{0,0,0,0},{0,0,0,0},{0,0,0,0}};
    #pragma unroll
    for (int mt = 0; mt < 4; ++mt)
        #pragma unroll
        for (int s = 0; s < 6; ++s) {
            u32x4 ga = *(const u32x4*)(gA + (size_t)((mt * 6 + s) * 64 + lane) * 8);
            acc[mt] = __builtin_amdgcn_mfma_f32_16x16x32_bf16(as_bf(ga), as_bf(bb[s]), acc[mt], 0, 0, 0);
        }

    const float* fr   = feat + (size_t)(nb + c) * 64;
    float*       orow = out  + (size_t)(nb + c) * 64;
    #pragma unroll
    for (int mt = 0; mt < 4; ++mt) {
        float4 f4 = *(const float4*)(fr + mt * 16 + g * 4);
        float4 o;
        float v0 = acc[mt][0] + f4.x; o.x = v0 > 0.f ? v0 : (__expf(v0) - 1.f);
        float v1 = acc[mt][1] + f4.y; o.y = v1 > 0.f ? v1 : (__expf(v1) - 1.f);
        float v2 = acc[mt][2] + f4.z; o.z = v2 > 0.f ? v2 : (__expf(v2) - 1.f);
        float v3 = acc[mt][3] + f4.w; o.w = v3 > 0.f ? v3 : (__expf(v3) - 1.f);
        *(float4*)(orow + mt * 16 + g * 4) = o;
    }
}

extern "C" void kernel_launch(void* const* d_in, const int* in_sizes, int n_in,
                              void* d_out, int out_size, void* d_ws, size_t ws_size,
                              hipStream_t stream) {
    const float* user_feat = (const float*)d_in[0];
    const float* item_feat = (const float*)d_in[1];
    const float* W_user    = (const float*)d_in[2];
    const float* W_item    = (const float*)d_in[3];
    const float* gate_u    = (const float*)d_in[4];
    const float* gate_i    = (const float*)d_in[5];
    const float* u_te      = (const float*)d_in[6];
    const float* u_te_k    = (const float*)d_in[7];
    const float* i_te      = (const float*)d_in[8];
    const float* i_te_k    = (const float*)d_in[9];
    const int*   user_nbr  = (const int*)d_in[10];
    const int*   item_nbr  = (const int*)d_in[11];
    const int*   user_time = (const int*)d_in[12];
    const int*   item_time = (const int*)d_in[13];

    ushort_t* hbf_u = (ushort_t*)d_ws;            // NU*64
    ushort_t* hbf_i = hbf_u + NU * DH;            // NI*64
    ushort_t* teA_u = hbf_i + NI * DH;            // 4096
    ushort_t* teA_i = teA_u + 4096;               // 4096
    ushort_t* gA_u  = teA_i + 4096;               // 12288
    ushort_t* gA_i  = gA_u + 12288;               // 12288
    ushort_t* cc_i  = gA_i + 12288;               // NI*192
    ushort_t* cc_u  = cc_i + (size_t)NI * 192;    // NU*192

    float* user_out = (float*)d_out;
    float* item_out = user_out + NU * DH;

    hipLaunchKernelGGL(prep_kernel, dim3(2), dim3(256), 0, stream,
                       gate_u, gate_i, u_te, i_te, u_te_k, i_te_k,
                       teA_u, teA_i, gA_u, gA_i);
    hipLaunchKernelGGL(proj_kernel, dim3(NU / 32), dim3(256), 0, stream,
                       user_feat, W_user, hbf_u, NU);
    hipLaunchKernelGGL(proj_kernel, dim3(NI / 32), dim3(256), 0, stream,
                       item_feat, W_item, hbf_i, NI);
    hipLaunchKernelGGL(agg_kernel, dim3(NI / 2), dim3(128), 0, stream,
                       hbf_u, hbf_i, item_nbr, item_time, teA_i, cc_i);
    hipLaunchKernelGGL(agg_kernel, dim3(NU / 2), dim3(128), 0, stream,
                       hbf_i, hbf_u, user_nbr, user_time, teA_u, cc_u);
    hipLaunchKernelGGL(epi_kernel, dim3(NI / 64), dim3(256), 0, stream,
                       cc_i, gA_i, item_feat, item_out);
    hipLaunchKernelGGL(epi_kernel, dim3(NU / 64), dim3(256), 0, stream,
                       cc_u, gA_u, user_feat, user_out);
}

// Round 7
// 175.774 us; speedup vs baseline: 1.0793x; 1.0724x over previous
//
#include <hip/hip_runtime.h>
#include <math.h>

#define NU 32768
#define NI 16384
#define DH 64
#define KK 50

typedef unsigned short ushort_t;
typedef __attribute__((ext_vector_type(8))) short  bf16x8;
typedef __attribute__((ext_vector_type(4))) float  f32x4;
typedef __attribute__((ext_vector_type(4))) unsigned int u32x4;

__device__ __forceinline__ unsigned cvtpk(float lo, float hi) {
    unsigned r;
    asm("v_cvt_pk_bf16_f32 %0, %1, %2" : "=v"(r) : "v"(lo), "v"(hi));
    return r;
}
__device__ __forceinline__ bf16x8 as_bf(u32x4 v) {
    union { u32x4 u; bf16x8 b; } x; x.u = v; return x.b;
}
__device__ __forceinline__ ushort_t bf16r(float v) {
    unsigned u = __float_as_uint(v);
    u += 0x7fffu + ((u >> 16) & 1u);
    return (ushort_t)(u >> 16);
}

// ---------------------------------------------------------------------------
// fusedA: blocks [0,1536) = proj (user then item); blocks 1536/1537 = prep.
// ---------------------------------------------------------------------------
__global__ __launch_bounds__(256) void fusedA_kernel(
    const float* __restrict__ user_feat, const float* __restrict__ item_feat,
    const float* __restrict__ W_user,    const float* __restrict__ W_item,
    const float* __restrict__ gate_u,    const float* __restrict__ gate_i,
    const float* __restrict__ u_te,      const float* __restrict__ i_te,
    const float* __restrict__ u_te_k,    const float* __restrict__ i_te_k,
    ushort_t* __restrict__ hbf_u, ushort_t* __restrict__ hbf_i,
    ushort_t* __restrict__ teA_u, ushort_t* __restrict__ teA_i,
    ushort_t* __restrict__ gA_u,  ushort_t* __restrict__ gA_i)
{
    __shared__ float SH[64 * 65];
    const int b = blockIdx.x;
    if (b < 1536) {
        const bool isU = b < 1024;
        const float* feat = isU ? user_feat : item_feat;
        const float* W    = isU ? W_user    : W_item;
        ushort_t*    hbf  = isU ? hbf_u     : hbf_i;
        const int    bb   = isU ? b : b - 1024;
        const int lane = threadIdx.x & 63;
        const int w = threadIdx.x >> 6;
        for (int i = threadIdx.x; i < 4096; i += 256)
            SH[(i >> 6) * 65 + (i & 63)] = W[i];
        __syncthreads();
        int row0 = bb * 32 + w * 8;
        for (int r = 0; r < 8; ++r) {
            int n = row0 + r;
            float fv = feat[n * DH + lane];
            float acc = 0.f;
            #pragma unroll
            for (int k = 0; k < DH; ++k)
                acc = fmaf(__shfl(fv, k), SH[lane * 65 + k], acc);
            hbf[n * DH + lane] = bf16r(acc);
        }
    } else {
        const int rel = b - 1536;
        const float* gate = rel ? gate_i : gate_u;
        const float* te   = rel ? i_te   : u_te;
        const float* tek  = rel ? i_te_k : u_te_k;
        ushort_t* teA = rel ? teA_i : teA_u;
        ushort_t* gA  = rel ? gA_i  : gA_u;
        float* M = SH;
        for (int o = threadIdx.x; o < 64 * 50; o += 256) {
            int d = o / 50, r = o % 50;
            float acc = 0.f;
            #pragma unroll 8
            for (int d2 = 0; d2 < 64; ++d2)
                acc = fmaf(gate[d * 128 + d2], tek[r * 64 + d2], acc);
            M[o] = acc;
        }
        __syncthreads();
        for (int i = threadIdx.x; i < 4096; i += 256) {
            int j = i & 7, l = (i >> 3) & 63, s = (i >> 9) & 1, t = i >> 10;
            int r = t * 16 + (l & 15);
            int d = s * 32 + ((l >> 4) & 3) * 8 + j;
            teA[i] = bf16r(r < KK ? te[r * DH + d] : 0.f);
        }
        for (int i = threadIdx.x; i < 12288; i += 256) {
            int j = i & 7, l = (i >> 3) & 63, q = i >> 9;
            int s = q % 6, mt = q / 6;
            int d = mt * 16 + (l & 15);
            int k = s * 32 + ((l >> 4) & 3) * 8 + j;
            float v = 0.f;
            if (k < 128)            v = gate[d * 128 + k];
            else if (k < 128 + KK)  v = M[d * 50 + (k - 128)];
            gA[i] = bf16r(v);
        }
    }
}

// ---------------------------------------------------------------------------
// agg: per-relation. 128 threads = 2 waves = 2 nodes, no __syncthreads.
// No forced min-waves (NO spills); no LDS mail (EB exchange only, 768B/wave).
// ---------------------------------------------------------------------------
__global__ __launch_bounds__(128) void agg_kernel(
    const ushort_t* __restrict__ h_src,
    const ushort_t* __restrict__ h_dst,
    const int*      __restrict__ nbr,
    const int*      __restrict__ times,
    const ushort_t* __restrict__ teA,
    ushort_t*       __restrict__ ccout)
{
    __shared__ __align__(16) float EBs[2][192];

    const int wid  = threadIdx.x >> 6;
    const int lane = threadIdx.x & 63;
    const int n    = blockIdx.x * 2 + wid;

    float* EB = EBs[wid];
    const int c = lane & 15;
    const int g = lane >> 4;

    int my_t = 0, my_nb = 0;
    if (lane < KK) {
        my_t  = times[n * KK + lane];
        my_nb = nbr[n * KK + lane];
    }

    // ---- gather register A-frags (verified layout) ----
    u32x4 af[4][2];
    #pragma unroll
    for (int t = 0; t < 4; ++t) {
        int r = t * 16 + c;
        int idx = __builtin_amdgcn_ds_bpermute(r << 2, my_nb);
        const ushort_t* src = h_src + idx * DH;
        #pragma unroll
        for (int s = 0; s < 2; ++s)
            af[t][s] = *(const u32x4*)(src + s * 32 + g * 8);
    }

    // ---- stable ranks ----
    int key = my_t * 64 + lane;
    int sro = 0;
    #pragma unroll
    for (int j = 0; j < KK; ++j) {
        int kj = __builtin_amdgcn_readlane(key, j);
        sro += (kj > key) ? 1 : 0;
    }

    // ---- last = first argmax(times) ----
    int key2 = (lane < KK) ? (my_t * 64 + (63 - lane)) : -1;
    #pragma unroll
    for (int off = 32; off >= 1; off >>= 1) {
        int o = __shfl_xor(key2, off);
        key2 = key2 > o ? key2 : o;
    }
    const int last   = __builtin_amdgcn_readfirstlane(63 - (key2 & 63));
    const int t_last = last >> 4;
    const int c_last = last & 15;

    // ---- B-fragments: col0 = dst(bf16), col1 = sle = mail[last] ----
    u32x4 fbv[2];
    {
        const ushort_t* hd = h_dst + n * DH;
        u32x4 sl0, sl1;
        if      (t_last == 0) { sl0 = af[0][0]; sl1 = af[0][1]; }
        else if (t_last == 1) { sl0 = af[1][0]; sl1 = af[1][1]; }
        else if (t_last == 2) { sl0 = af[2][0]; sl1 = af[2][1]; }
        else                  { sl0 = af[3][0]; sl1 = af[3][1]; }
        const int ba = ((lane & 48) + c_last) << 2;
        const bool is1 = (c == 1);
        #pragma unroll
        for (int s = 0; s < 2; ++s) {
            u32x4 dp = *(const u32x4*)(hd + s * 32 + g * 8);
            u32x4 sl = (s == 0) ? sl0 : sl1;
            u32x4 fb;
            #pragma unroll
            for (int u = 0; u < 4; ++u) {
                unsigned sv = (unsigned)__builtin_amdgcn_ds_bpermute(ba, (int)sl[u]);
                fb[u] = is1 ? sv : dp[u];
            }
            fbv[s] = fb;
        }
    }

    // ---- dot MFMA: e (col0), e1 (col1) ----
    #pragma unroll
    for (int t = 0; t < 4; ++t) {
        f32x4 acc = {0.f, 0.f, 0.f, 0.f};
        #pragma unroll
        for (int s = 0; s < 2; ++s)
            acc = __builtin_amdgcn_mfma_f32_16x16x32_bf16(as_bf(af[t][s]), as_bf(fbv[s]), acc, 0, 0, 0);
        if (c < 2) {
            float* eb = EB + c * 64 + t * 16 + g * 4;
            eb[0] = acc[0]; eb[1] = acc[1]; eb[2] = acc[2]; eb[3] = acc[3];
        }
    }

    // ---- tp MFMA (teA tiles) ----
    #pragma unroll
    for (int t = 0; t < 4; ++t) {
        f32x4 acc = {0.f, 0.f, 0.f, 0.f};
        #pragma unroll
        for (int s = 0; s < 2; ++s) {
            u32x4 ta = *(const u32x4*)(teA + ((t * 2 + s) * 64 + lane) * 8);
            acc = __builtin_amdgcn_mfma_f32_16x16x32_bf16(as_bf(ta), as_bf(fbv[s]), acc, 0, 0, 0);
        }
        if (c == 0) {
            float* eb = EB + 128 + t * 16 + g * 4;
            eb[0] = acc[0]; eb[1] = acc[1]; eb[2] = acc[2]; eb[3] = acc[3];
        }
    }

    // ---- softmax at lane = k ----
    float eraw  = EB[lane];
    float e1raw = EB[64 + lane];
    float tpown = EB[128 + lane];
    float tps = __uint_as_float(__builtin_amdgcn_ds_bpermute(sro << 2, __float_as_uint(tpown)));
    float e  = (lane < KK) ? (eraw + tps) * 0.125f : -INFINITY;
    float e1 = (lane < KK) ? e1raw * 0.125f        : -INFINITY;
    float m = e, m1 = e1;
    #pragma unroll
    for (int off = 32; off >= 1; off >>= 1) {
        m  = fmaxf(m,  __shfl_xor(m,  off));
        m1 = fmaxf(m1, __shfl_xor(m1, off));
    }
    float p  = (lane < KK) ? __expf(e - m)   : 0.f;
    float p1 = (lane < KK) ? __expf(e1 - m1) : 0.f;
    float s = p, s1 = p1;
    #pragma unroll
    for (int off = 32; off >= 1; off >>= 1) {
        s  += __shfl_xor(s,  off);
        s1 += __shfl_xor(s1, off);
    }
    float al  = p  * __builtin_amdgcn_rcpf(s);
    float al1 = p1 * __builtin_amdgcn_rcpf(s1);

    // ---- beta scatter + cc store ----
    ushort_t* ccr = ccout + (size_t)n * 192;
    {
        int pushaddr = ((lane < KK) ? sro : lane) << 2;
        float beta = __uint_as_float(__builtin_amdgcn_ds_permute(pushaddr, __float_as_uint(al)));
        ccr[128 + lane] = bf16r(beta);
    }

    // ---- weighted sums (lane = d): re-read mail rows from hbf (L2-hot) ----
    unsigned apk = cvtpk(al, al1);
    float hl = 0.f, hs = 0.f;
    #pragma unroll 10
    for (int k = 0; k < KK; ++k) {
        int idx = __builtin_amdgcn_readlane(my_nb, k);
        unsigned a = (unsigned)__builtin_amdgcn_readlane((int)apk, k);
        ushort_t u = h_src[(size_t)idx * DH + lane];
        float mv = __uint_as_float(((unsigned)u) << 16);
        hl = fmaf(__uint_as_float(a << 16), mv, hl);
        hs = fmaf(__uint_as_float(a & 0xffff0000u), mv, hs);
    }
    unsigned hp = cvtpk(hl, hs);
    ccr[lane]      = (ushort_t)hp;
    ccr[64 + lane] = (ushort_t)(hp >> 16);
}

// ---------------------------------------------------------------------------
// epi: per-relation batched gate GEMM. 1 wave = 16 nodes.
// ---------------------------------------------------------------------------
__global__ __launch_bounds__(256) void epi_kernel(
    const ushort_t* __restrict__ cc,
    const ushort_t* __restrict__ gA,
    const float*    __restrict__ feat,
    float*          __restrict__ out)
{
    const int w    = threadIdx.x >> 6;
    const int lane = threadIdx.x & 63;
    const int c = lane & 15, g = lane >> 4;
    const int nb = (blockIdx.x * 4 + w) * 16;

    const char* ccr = (const char*)(cc + (size_t)(nb + c) * 192);
    u32x4 bb6[6];
    #pragma unroll
    for (int s = 0; s < 6; ++s)
        bb6[s] = *(const u32x4*)(ccr + s * 64 + g * 16);

    f32x4 acc[4] = {{0,0,0,0},{0,0,0,0},{0,0,0,0},{0,0,0,0}};
    #pragma unroll
    for (int mt = 0; mt < 4; ++mt)
        #pragma unroll
        for (int s = 0; s < 6; ++s) {
            u32x4 ga = *(const u32x4*)(gA + (size_t)((mt * 6 + s) * 64 + lane) * 8);
            acc[mt] = __builtin_amdgcn_mfma_f32_16x16x32_bf16(as_bf(ga), as_bf(bb6[s]), acc[mt], 0, 0, 0);
        }

    const float* fr   = feat + (size_t)(nb + c) * 64;
    float*       orow = out  + (size_t)(nb + c) * 64;
    #pragma unroll
    for (int mt = 0; mt < 4; ++mt) {
        float4 f4 = *(const float4*)(fr + mt * 16 + g * 4);
        float4 o;
        float v0 = acc[mt][0] + f4.x; o.x = v0 > 0.f ? v0 : (__expf(v0) - 1.f);
        float v1 = acc[mt][1] + f4.y; o.y = v1 > 0.f ? v1 : (__expf(v1) - 1.f);
        float v2 = acc[mt][2] + f4.z; o.z = v2 > 0.f ? v2 : (__expf(v2) - 1.f);
        float v3 = acc[mt][3] + f4.w; o.w = v3 > 0.f ? v3 : (__expf(v3) - 1.f);
        *(float4*)(orow + mt * 16 + g * 4) = o;
    }
}

extern "C" void kernel_launch(void* const* d_in, const int* in_sizes, int n_in,
                              void* d_out, int out_size, void* d_ws, size_t ws_size,
                              hipStream_t stream) {
    const float* user_feat = (const float*)d_in[0];
    const float* item_feat = (const float*)d_in[1];
    const float* W_user    = (const float*)d_in[2];
    const float* W_item    = (const float*)d_in[3];
    const float* gate_u    = (const float*)d_in[4];
    const float* gate_i    = (const float*)d_in[5];
    const float* u_te      = (const float*)d_in[6];
    const float* u_te_k    = (const float*)d_in[7];
    const float* i_te      = (const float*)d_in[8];
    const float* i_te_k    = (const float*)d_in[9];
    const int*   user_nbr  = (const int*)d_in[10];
    const int*   item_nbr  = (const int*)d_in[11];
    const int*   user_time = (const int*)d_in[12];
    const int*   item_time = (const int*)d_in[13];

    ushort_t* hbf_u = (ushort_t*)d_ws;            // NU*64
    ushort_t* hbf_i = hbf_u + NU * DH;            // NI*64
    ushort_t* teA_u = hbf_i + NI * DH;            // 4096
    ushort_t* teA_i = teA_u + 4096;               // 4096
    ushort_t* gA_u  = teA_i + 4096;               // 12288
    ushort_t* gA_i  = gA_u + 12288;               // 12288
    ushort_t* cc_i  = gA_i + 12288;               // NI*192
    ushort_t* cc_u  = cc_i + (size_t)NI * 192;    // NU*192

    float* user_out = (float*)d_out;
    float* item_out = user_out + NU * DH;

    hipLaunchKernelGGL(fusedA_kernel, dim3(1538), dim3(256), 0, stream,
                       user_feat, item_feat, W_user, W_item, gate_u, gate_i,
                       u_te, i_te, u_te_k, i_te_k,
                       hbf_u, hbf_i, teA_u, teA_i, gA_u, gA_i);
    hipLaunchKernelGGL(agg_kernel, dim3(NI / 2), dim3(128), 0, stream,
                       hbf_u, hbf_i, item_nbr, item_time, teA_i, cc_i);
    hipLaunchKernelGGL(agg_kernel, dim3(NU / 2), dim3(128), 0, stream,
                       hbf_i, hbf_u, user_nbr, user_time, teA_u, cc_u);
    hipLaunchKernelGGL(epi_kernel, dim3(NI / 64), dim3(256), 0, stream,
                       cc_i, gA_i, item_feat, item_out);
    hipLaunchKernelGGL(epi_kernel, dim3(NU / 64), dim3(256), 0, stream,
                       cc_u, gA_u, user_feat, user_out);
}

// Round 8
// 126.377 us; speedup vs baseline: 1.5011x; 1.3909x over previous
//
#include <hip/hip_runtime.h>
#include <math.h>

#define NU 32768
#define NI 16384
#define DH 64
#define KK 50

typedef unsigned short ushort_t;
typedef __attribute__((ext_vector_type(8))) short  bf16x8;
typedef __attribute__((ext_vector_type(4))) float  f32x4;
typedef __attribute__((ext_vector_type(4))) unsigned int u32x4;

__device__ __forceinline__ unsigned cvtpk(float lo, float hi) {
    unsigned r;
    asm("v_cvt_pk_bf16_f32 %0, %1, %2" : "=v"(r) : "v"(lo), "v"(hi));
    return r;
}
__device__ __forceinline__ bf16x8 as_bf(u32x4 v) {
    union { u32x4 u; bf16x8 b; } x; x.u = v; return x.b;
}
__device__ __forceinline__ ushort_t bf16r(float v) {
    unsigned u = __float_as_uint(v);
    u += 0x7fffu + ((u >> 16) & 1u);
    return (ushort_t)(u >> 16);
}
__device__ __forceinline__ u32x4 pk8(const float* p) {
    float4 a = *(const float4*)p;
    float4 b = *(const float4*)(p + 4);
    u32x4 r;
    r[0] = cvtpk(a.x, a.y); r[1] = cvtpk(a.z, a.w);
    r[2] = cvtpk(b.x, b.y); r[3] = cvtpk(b.z, b.w);
    return r;
}

// ---------------------------------------------------------------------------
// projprep: blocks [0,768) = proj via MFMA; blocks 768/769 = prep (M via MFMA
// + teA/gA tiling). All fragment layouts are the R4/R5-verified ones:
//   A-tile:  tile[((mt*2+s)*64 + l)*8 + j] = A[16mt+(l&15)][32s+8*((l>>4)&3)+j]
//   B-frag:  lane(g,c): col=c, k = 32s + 8g + j   (epi-verified)
//   C:       col = lane&15, row(d) = mt*16 + g*4 + jj (epi-verified)
// ---------------------------------------------------------------------------
__global__ __launch_bounds__(256) void projprep_kernel(
    const float* __restrict__ user_feat, const float* __restrict__ item_feat,
    const float* __restrict__ W_user,    const float* __restrict__ W_item,
    const float* __restrict__ gate_u,    const float* __restrict__ gate_i,
    const float* __restrict__ u_te,      const float* __restrict__ i_te,
    const float* __restrict__ u_te_k,    const float* __restrict__ i_te_k,
    ushort_t* __restrict__ hbf_u, ushort_t* __restrict__ hbf_i,
    ushort_t* __restrict__ teA_u, ushort_t* __restrict__ teA_i,
    ushort_t* __restrict__ gA_u,  ushort_t* __restrict__ gA_i)
{
    __shared__ __align__(16) float SH[3200];   // prep: M f32[64][50]; proj: WA alias
    const int b    = blockIdx.x;
    const int tid  = threadIdx.x;
    const int w    = tid >> 6;
    const int lane = tid & 63;
    const int c = lane & 15, g = lane >> 4;

    if (b < 768) {
        // ================= proj: h = feat @ W.T, 16 rows/wave =================
        const bool isU = b < 512;
        const float* feat = isU ? user_feat : item_feat;
        const float* W    = isU ? W_user    : W_item;
        ushort_t*    hbf  = isU ? hbf_u     : hbf_i;
        const int    bb   = isU ? b : b - 512;

        ushort_t* WA = (ushort_t*)SH;
        for (int i = tid; i < 4096; i += 256) {
            int j = i & 7, l = (i >> 3) & 63, s = (i >> 9) & 1, mt = i >> 10;
            int row = mt * 16 + (l & 15);
            int k   = s * 32 + ((l >> 4) & 3) * 8 + j;
            WA[i] = bf16r(W[row * DH + k]);
        }
        __syncthreads();

        const int nb = bb * 64 + w * 16;
        u32x4 bf[2];
        #pragma unroll
        for (int s = 0; s < 2; ++s)
            bf[s] = pk8(feat + (size_t)(nb + c) * DH + s * 32 + g * 8);

        #pragma unroll
        for (int mt = 0; mt < 4; ++mt) {
            f32x4 acc = {0.f, 0.f, 0.f, 0.f};
            #pragma unroll
            for (int s = 0; s < 2; ++s) {
                u32x4 af = *(const u32x4*)(WA + ((mt * 2 + s) * 64 + lane) * 8);
                acc = __builtin_amdgcn_mfma_f32_16x16x32_bf16(as_bf(af), as_bf(bf[s]), acc, 0, 0, 0);
            }
            uint2 p;
            p.x = cvtpk(acc[0], acc[1]);
            p.y = cvtpk(acc[2], acc[3]);
            *(uint2*)(hbf + (size_t)(nb + c) * DH + mt * 16 + g * 4) = p;
        }
    } else {
        // ================= prep: M via MFMA, then teA / gA tiles ==============
        const int rel = b - 768;
        const float* gate = rel ? gate_i : gate_u;
        const float* te   = rel ? i_te   : u_te;
        const float* tek  = rel ? i_te_k : u_te_k;
        ushort_t* teA = rel ? teA_i : teA_u;
        ushort_t* gA  = rel ? gA_i  : gA_u;
        float* M = SH;

        // ---- M[d][r] = sum_k gate[d][k] * tek[r][k]  (k<64), wave w = d-tile ----
        {
            const int d = w * 16 + c;
            u32x4 ga[2];
            #pragma unroll
            for (int s = 0; s < 2; ++s)
                ga[s] = pk8(gate + (size_t)d * 128 + s * 32 + g * 8);
            #pragma unroll
            for (int rt = 0; rt < 4; ++rt) {
                int r = rt * 16 + c;
                const float* tr = tek + (size_t)(r < KK ? r : 0) * DH;
                f32x4 acc = {0.f, 0.f, 0.f, 0.f};
                #pragma unroll
                for (int s = 0; s < 2; ++s) {
                    u32x4 bfr = pk8(tr + s * 32 + g * 8);
                    acc = __builtin_amdgcn_mfma_f32_16x16x32_bf16(as_bf(ga[s]), as_bf(bfr), acc, 0, 0, 0);
                }
                if (r < KK) {
                    #pragma unroll
                    for (int jj = 0; jj < 4; ++jj)
                        M[(w * 16 + g * 4 + jj) * KK + r] = acc[jj];
                }
            }
        }
        __syncthreads();

        // ---- teA tiles (verified) ----
        for (int i = tid; i < 4096; i += 256) {
            int j = i & 7, l = (i >> 3) & 63, s = (i >> 9) & 1, t = i >> 10;
            int r = t * 16 + (l & 15);
            int d = s * 32 + ((l >> 4) & 3) * 8 + j;
            teA[i] = bf16r(r < KK ? te[r * DH + d] : 0.f);
        }
        // ---- gA tiles of [gate | M] (verified) ----
        for (int i = tid; i < 12288; i += 256) {
            int j = i & 7, l = (i >> 3) & 63, q = i >> 9;
            int s = q % 6, mt = q / 6;
            int d = mt * 16 + (l & 15);
            int k = s * 32 + ((l >> 4) & 3) * 8 + j;
            float v = 0.f;
            if (k < 128)            v = gate[d * 128 + k];
            else if (k < 128 + KK)  v = M[d * KK + (k - 128)];
            gA[i] = bf16r(v);
        }
    }
}

// ---------------------------------------------------------------------------
// agg: per-relation. 128 threads = 2 waves = 2 nodes, no __syncthreads.
// (byte-identical to R7 — passed post-timing validation)
// ---------------------------------------------------------------------------
__global__ __launch_bounds__(128) void agg_kernel(
    const ushort_t* __restrict__ h_src,
    const ushort_t* __restrict__ h_dst,
    const int*      __restrict__ nbr,
    const int*      __restrict__ times,
    const ushort_t* __restrict__ teA,
    ushort_t*       __restrict__ ccout)
{
    __shared__ __align__(16) float EBs[2][192];

    const int wid  = threadIdx.x >> 6;
    const int lane = threadIdx.x & 63;
    const int n    = blockIdx.x * 2 + wid;

    float* EB = EBs[wid];
    const int c = lane & 15;
    const int g = lane >> 4;

    int my_t = 0, my_nb = 0;
    if (lane < KK) {
        my_t  = times[n * KK + lane];
        my_nb = nbr[n * KK + lane];
    }

    // ---- gather register A-frags ----
    u32x4 af[4][2];
    #pragma unroll
    for (int t = 0; t < 4; ++t) {
        int r = t * 16 + c;
        int idx = __builtin_amdgcn_ds_bpermute(r << 2, my_nb);
        const ushort_t* src = h_src + idx * DH;
        #pragma unroll
        for (int s = 0; s < 2; ++s)
            af[t][s] = *(const u32x4*)(src + s * 32 + g * 8);
    }

    // ---- stable ranks ----
    int key = my_t * 64 + lane;
    int sro = 0;
    #pragma unroll
    for (int j = 0; j < KK; ++j) {
        int kj = __builtin_amdgcn_readlane(key, j);
        sro += (kj > key) ? 1 : 0;
    }

    // ---- last = first argmax(times) ----
    int key2 = (lane < KK) ? (my_t * 64 + (63 - lane)) : -1;
    #pragma unroll
    for (int off = 32; off >= 1; off >>= 1) {
        int o = __shfl_xor(key2, off);
        key2 = key2 > o ? key2 : o;
    }
    const int last   = __builtin_amdgcn_readfirstlane(63 - (key2 & 63));
    const int t_last = last >> 4;
    const int c_last = last & 15;

    // ---- B-fragments: col0 = dst(bf16), col1 = sle = mail[last] ----
    u32x4 fbv[2];
    {
        const ushort_t* hd = h_dst + n * DH;
        u32x4 sl0, sl1;
        if      (t_last == 0) { sl0 = af[0][0]; sl1 = af[0][1]; }
        else if (t_last == 1) { sl0 = af[1][0]; sl1 = af[1][1]; }
        else if (t_last == 2) { sl0 = af[2][0]; sl1 = af[2][1]; }
        else                  { sl0 = af[3][0]; sl1 = af[3][1]; }
        const int ba = ((lane & 48) + c_last) << 2;
        const bool is1 = (c == 1);
        #pragma unroll
        for (int s = 0; s < 2; ++s) {
            u32x4 dp = *(const u32x4*)(hd + s * 32 + g * 8);
            u32x4 sl = (s == 0) ? sl0 : sl1;
            u32x4 fb;
            #pragma unroll
            for (int u = 0; u < 4; ++u) {
                unsigned sv = (unsigned)__builtin_amdgcn_ds_bpermute(ba, (int)sl[u]);
                fb[u] = is1 ? sv : dp[u];
            }
            fbv[s] = fb;
        }
    }

    // ---- dot MFMA: e (col0), e1 (col1) ----
    #pragma unroll
    for (int t = 0; t < 4; ++t) {
        f32x4 acc = {0.f, 0.f, 0.f, 0.f};
        #pragma unroll
        for (int s = 0; s < 2; ++s)
            acc = __builtin_amdgcn_mfma_f32_16x16x32_bf16(as_bf(af[t][s]), as_bf(fbv[s]), acc, 0, 0, 0);
        if (c < 2) {
            float* eb = EB + c * 64 + t * 16 + g * 4;
            eb[0] = acc[0]; eb[1] = acc[1]; eb[2] = acc[2]; eb[3] = acc[3];
        }
    }

    // ---- tp MFMA (teA tiles) ----
    #pragma unroll
    for (int t = 0; t < 4; ++t) {
        f32x4 acc = {0.f, 0.f, 0.f, 0.f};
        #pragma unroll
        for (int s = 0; s < 2; ++s) {
            u32x4 ta = *(const u32x4*)(teA + ((t * 2 + s) * 64 + lane) * 8);
            acc = __builtin_amdgcn_mfma_f32_16x16x32_bf16(as_bf(ta), as_bf(fbv[s]), acc, 0, 0, 0);
        }
        if (c == 0) {
            float* eb = EB + 128 + t * 16 + g * 4;
            eb[0] = acc[0]; eb[1] = acc[1]; eb[2] = acc[2]; eb[3] = acc[3];
        }
    }

    // ---- softmax at lane = k ----
    float eraw  = EB[lane];
    float e1raw = EB[64 + lane];
    float tpown = EB[128 + lane];
    float tps = __uint_as_float(__builtin_amdgcn_ds_bpermute(sro << 2, __float_as_uint(tpown)));
    float e  = (lane < KK) ? (eraw + tps) * 0.125f : -INFINITY;
    float e1 = (lane < KK) ? e1raw * 0.125f        : -INFINITY;
    float m = e, m1 = e1;
    #pragma unroll
    for (int off = 32; off >= 1; off >>= 1) {
        m  = fmaxf(m,  __shfl_xor(m,  off));
        m1 = fmaxf(m1, __shfl_xor(m1, off));
    }
    float p  = (lane < KK) ? __expf(e - m)   : 0.f;
    float p1 = (lane < KK) ? __expf(e1 - m1) : 0.f;
    float s = p, s1 = p1;
    #pragma unroll
    for (int off = 32; off >= 1; off >>= 1) {
        s  += __shfl_xor(s,  off);
        s1 += __shfl_xor(s1, off);
    }
    float al  = p  * __builtin_amdgcn_rcpf(s);
    float al1 = p1 * __builtin_amdgcn_rcpf(s1);

    // ---- beta scatter + cc store ----
    ushort_t* ccr = ccout + (size_t)n * 192;
    {
        int pushaddr = ((lane < KK) ? sro : lane) << 2;
        float beta = __uint_as_float(__builtin_amdgcn_ds_permute(pushaddr, __float_as_uint(al)));
        ccr[128 + lane] = bf16r(beta);
    }

    // ---- weighted sums (lane = d): re-read mail rows from hbf (L2-hot) ----
    unsigned apk = cvtpk(al, al1);
    float hl = 0.f, hs = 0.f;
    #pragma unroll 10
    for (int k = 0; k < KK; ++k) {
        int idx = __builtin_amdgcn_readlane(my_nb, k);
        unsigned a = (unsigned)__builtin_amdgcn_readlane((int)apk, k);
        ushort_t u = h_src[(size_t)idx * DH + lane];
        float mv = __uint_as_float(((unsigned)u) << 16);
        hl = fmaf(__uint_as_float(a << 16), mv, hl);
        hs = fmaf(__uint_as_float(a & 0xffff0000u), mv, hs);
    }
    unsigned hp = cvtpk(hl, hs);
    ccr[lane]      = (ushort_t)hp;
    ccr[64 + lane] = (ushort_t)(hp >> 16);
}

// ---------------------------------------------------------------------------
// epi: per-relation batched gate GEMM. 1 wave = 16 nodes. (R7-verified)
// ---------------------------------------------------------------------------
__global__ __launch_bounds__(256) void epi_kernel(
    const ushort_t* __restrict__ cc,
    const ushort_t* __restrict__ gA,
    const float*    __restrict__ feat,
    float*          __restrict__ out)
{
    const int w    = threadIdx.x >> 6;
    const int lane = threadIdx.x & 63;
    const int c = lane & 15, g = lane >> 4;
    const int nb = (blockIdx.x * 4 + w) * 16;

    const char* ccr = (const char*)(cc + (size_t)(nb + c) * 192);
    u32x4 bb6[6];
    #pragma unroll
    for (int s = 0; s < 6; ++s)
        bb6[s] = *(const u32x4*)(ccr + s * 64 + g * 16);

    f32x4 acc[4] = {{0,0,0,0},{0,0,0,0},{0,0,0,0},{0,0,0,0}};
    #pragma unroll
    for (int mt = 0; mt < 4; ++mt)
        #pragma unroll
        for (int s = 0; s < 6; ++s) {
            u32x4 ga = *(const u32x4*)(gA + (size_t)((mt * 6 + s) * 64 + lane) * 8);
            acc[mt] = __builtin_amdgcn_mfma_f32_16x16x32_bf16(as_bf(ga), as_bf(bb6[s]), acc[mt], 0, 0, 0);
        }

    const float* fr   = feat + (size_t)(nb + c) * 64;
    float*       orow = out  + (size_t)(nb + c) * 64;
    #pragma unroll
    for (int mt = 0; mt < 4; ++mt) {
        float4 f4 = *(const float4*)(fr + mt * 16 + g * 4);
        float4 o;
        float v0 = acc[mt][0] + f4.x; o.x = v0 > 0.f ? v0 : (__expf(v0) - 1.f);
        float v1 = acc[mt][1] + f4.y; o.y = v1 > 0.f ? v1 : (__expf(v1) - 1.f);
        float v2 = acc[mt][2] + f4.z; o.z = v2 > 0.f ? v2 : (__expf(v2) - 1.f);
        float v3 = acc[mt][3] + f4.w; o.w = v3 > 0.f ? v3 : (__expf(v3) - 1.f);
        *(float4*)(orow + mt * 16 + g * 4) = o;
    }
}

extern "C" void kernel_launch(void* const* d_in, const int* in_sizes, int n_in,
                              void* d_out, int out_size, void* d_ws, size_t ws_size,
                              hipStream_t stream) {
    const float* user_feat = (const float*)d_in[0];
    const float* item_feat = (const float*)d_in[1];
    const float* W_user    = (const float*)d_in[2];
    const float* W_item    = (const float*)d_in[3];
    const float* gate_u    = (const float*)d_in[4];
    const float* gate_i    = (const float*)d_in[5];
    const float* u_te      = (const float*)d_in[6];
    const float* u_te_k    = (const float*)d_in[7];
    const float* i_te      = (const float*)d_in[8];
    const float* i_te_k    = (const float*)d_in[9];
    const int*   user_nbr  = (const int*)d_in[10];
    const int*   item_nbr  = (const int*)d_in[11];
    const int*   user_time = (const int*)d_in[12];
    const int*   item_time = (const int*)d_in[13];

    ushort_t* hbf_u = (ushort_t*)d_ws;            // NU*64
    ushort_t* hbf_i = hbf_u + NU * DH;            // NI*64
    ushort_t* teA_u = hbf_i + NI * DH;            // 4096
    ushort_t* teA_i = teA_u + 4096;               // 4096
    ushort_t* gA_u  = teA_i + 4096;               // 12288
    ushort_t* gA_i  = gA_u + 12288;               // 12288
    ushort_t* cc_i  = gA_i + 12288;               // NI*192
    ushort_t* cc_u  = cc_i + (size_t)NI * 192;    // NU*192

    float* user_out = (float*)d_out;
    float* item_out = user_out + NU * DH;

    hipLaunchKernelGGL(projprep_kernel, dim3(770), dim3(256), 0, stream,
                       user_feat, item_feat, W_user, W_item, gate_u, gate_i,
                       u_te, i_te, u_te_k, i_te_k,
                       hbf_u, hbf_i, teA_u, teA_i, gA_u, gA_i);
    hipLaunchKernelGGL(agg_kernel, dim3(NI / 2), dim3(128), 0, stream,
                       hbf_u, hbf_i, item_nbr, item_time, teA_i, cc_i);
    hipLaunchKernelGGL(agg_kernel, dim3(NU / 2), dim3(128), 0, stream,
                       hbf_i, hbf_u, user_nbr, user_time, teA_u, cc_u);
    hipLaunchKernelGGL(epi_kernel, dim3(NI / 64), dim3(256), 0, stream,
                       cc_i, gA_i, item_feat, item_out);
    hipLaunchKernelGGL(epi_kernel, dim3(NU / 64), dim3(256), 0, stream,
                       cc_u, gA_u, user_feat, user_out);
}